// Round 1
// baseline (2331.969 us; speedup 1.0000x reference)
//
#include <hip/hip_runtime.h>
#include <cstddef>
#include <cstdint>
#include <math.h>

#define BB   4
#define TT   2048
#define CCH  1024
#define HH   16
#define DD   64
#define CSZ  16
#define NTC  128
#define EPSF 1e-5f

__device__ __forceinline__ float wave_sum(float v) {
#pragma unroll
  for (int off = 32; off > 0; off >>= 1) v += __shfl_xor(v, off, 64);
  return v;
}

// C = A(lda) @ W + bias ; A: MxK row-major w/ stride lda, W: KxN row-major, C: MxN (ldc = N)
// M % 128 == 0, K % 16 == 0. N bounds-checked.
__global__ __launch_bounds__(256) void gemm_f32(
    const float* __restrict__ A, int lda,
    const float* __restrict__ W,
    const float* __restrict__ bias,
    float* __restrict__ C, int M, int N, int K) {
  __shared__ float As[16][132];   // [k][m], padded to break store conflicts
  __shared__ float Bs[16][128];   // [k][n]
  const int tid  = threadIdx.x;
  const int row0 = blockIdx.y * 128;
  const int col0 = blockIdx.x * 128;
  const int ty = tid >> 4;         // 0..15 (m dir)
  const int tx = tid & 15;         // 0..15 (n dir)
  const int a_r = tid >> 2;        // 0..63
  const int a_k = (tid & 3) << 2;  // 0,4,8,12
  const int b_r = tid >> 5;        // 0..7
  const int b_c = (tid & 31) << 2; // 0..124

  float acc[8][8];
#pragma unroll
  for (int i = 0; i < 8; i++)
#pragma unroll
    for (int j = 0; j < 8; j++) acc[i][j] = 0.f;

  for (int k0 = 0; k0 < K; k0 += 16) {
#pragma unroll
    for (int i = 0; i < 2; i++) {
      int r = a_r + i * 64;
      float4 av = *(const float4*)(A + (size_t)(row0 + r) * lda + (k0 + a_k));
      As[a_k + 0][r] = av.x;
      As[a_k + 1][r] = av.y;
      As[a_k + 2][r] = av.z;
      As[a_k + 3][r] = av.w;
    }
#pragma unroll
    for (int i = 0; i < 2; i++) {
      int r = b_r + i * 8;
      int gc = col0 + b_c;
      float4 bv = make_float4(0.f, 0.f, 0.f, 0.f);
      if (gc < N) bv = *(const float4*)(W + (size_t)(k0 + r) * N + gc);
      *(float4*)(&Bs[r][b_c]) = bv;
    }
    __syncthreads();
#pragma unroll
    for (int kk = 0; kk < 16; kk++) {
      float af[8], bf[8];
      *(float4*)&af[0] = *(const float4*)&As[kk][ty * 8];
      *(float4*)&af[4] = *(const float4*)&As[kk][ty * 8 + 4];
      *(float4*)&bf[0] = *(const float4*)&Bs[kk][tx * 8];
      *(float4*)&bf[4] = *(const float4*)&Bs[kk][tx * 8 + 4];
#pragma unroll
      for (int i = 0; i < 8; i++)
#pragma unroll
        for (int j = 0; j < 8; j++) acc[i][j] += af[i] * bf[j];
    }
    __syncthreads();
  }
#pragma unroll
  for (int i = 0; i < 8; i++) {
    int r = row0 + ty * 8 + i;
#pragma unroll
    for (int j0 = 0; j0 < 8; j0 += 4) {
      int cc = col0 + tx * 8 + j0;
      if (cc < N) {
        float4 ov;
        ov.x = acc[i][j0 + 0] + bias[cc + 0];
        ov.y = acc[i][j0 + 1] + bias[cc + 1];
        ov.z = acc[i][j0 + 2] + bias[cc + 2];
        ov.w = acc[i][j0 + 3] + bias[cc + 3];
        *(float4*)(C + (size_t)r * N + cc) = ov;
      }
    }
  }
}

// L2-normalize q and k rows (length 64) in-place inside the qkv buffer.
// One wave per row. rows = B*T*2*H.
__global__ __launch_bounds__(256) void normalize_qk(float* __restrict__ qkv) {
  const int idx = blockIdx.x * 4 + (threadIdx.x >> 6);
  const int l = threadIdx.x & 63;
  const int rowBT = idx >> 5;        // / (2*H)
  const int rem = idx & 31;
  const int which = rem >> 4;        // 0 = q, 1 = k
  const int h = rem & 15;
  const size_t addr = (size_t)rowBT * 3072 + (size_t)which * 1024 + h * 64 + l;
  float v = qkv[addr];
  float ss = wave_sum(v * v);
  float nrm = sqrtf(ss);
  float sc = 1.f / fmaxf(nrm, 1e-12f);
  qkv[addr] = v * sc;
}

// Titans recurrence. One block per (b,h). 256 threads = 4 waves.
// Thread (w = tid/64, l = tid%64) owns S[w*16+r][l], M[w*16+r][l] in registers.
// Writes LN(o) into the (consumed) v-slot of qkv: col offset 2048.
__global__ __launch_bounds__(256) void titans_rec(
    float* __restrict__ qkv, const float* __restrict__ p,
    const float* __restrict__ w, const float* __restrict__ bparm) {
  const int bh = blockIdx.x;
  const int b = bh >> 4;
  const int h = bh & 15;
  const int tid = threadIdx.x;
  const int wv = tid >> 6;
  const int l = tid & 63;

  __shared__ float k_s[CSZ][DD];
  __shared__ float v_s[CSZ][DD];
  __shared__ float q_s[CSZ][DD];
  __shared__ float dkh_s[CSZ][DD];
  __shared__ float part[4][CSZ][DD];
  __shared__ float th_s[CSZ], al_s[CSZ], et_s[CSZ];

  float S[16], M[16];
#pragma unroll
  for (int r = 0; r < 16; r++) { S[r] = 0.f; M[r] = 0.f; }

  const float w_l = w[h * DD + l];
  const float b_l = bparm[h * DD + l];

  float* qbase = qkv + (size_t)(b * TT) * 3072 + h * DD;
  const float* pbase = p + (size_t)(b * TT) * 48 + h * 3;

  for (int nt = 0; nt < NTC; nt++) {
    // ---- load chunk tiles ----
    for (int cc = wv; cc < CSZ; cc += 4) {
      size_t roff = (size_t)(nt * CSZ + cc) * 3072 + l;
      q_s[cc][l] = qbase[roff];
      k_s[cc][l] = qbase[roff + 1024];
      v_s[cc][l] = qbase[roff + 2048];
    }
    if (tid < CSZ) {
      const float* pp = pbase + (size_t)(nt * CSZ + tid) * 48;
      th_s[tid] = 1.f / (1.f + expf(-pp[0]));
      al_s[tid] = 1.f / (1.f + expf(-pp[1]));
      et_s[tid] = 1.f / (1.f + expf(-pp[2]));
    }
    __syncthreads();

    // ---- kh = k @ S (partial over this wave's 16 rows) ----
#pragma unroll 4
    for (int c = 0; c < CSZ; c++) {
      float kf[16];
      *(float4*)&kf[0]  = *(const float4*)&k_s[c][wv * 16];
      *(float4*)&kf[4]  = *(const float4*)&k_s[c][wv * 16 + 4];
      *(float4*)&kf[8]  = *(const float4*)&k_s[c][wv * 16 + 8];
      *(float4*)&kf[12] = *(const float4*)&k_s[c][wv * 16 + 12];
      float s = 0.f;
#pragma unroll
      for (int r = 0; r < 16; r++) s += kf[r] * S[r];
      part[wv][c][l] = s;
    }
    __syncthreads();

    // ---- LN fwd + bwd: rows c = wv, wv+4, wv+8, wv+12 (one wave per row) ----
#pragma unroll
    for (int ci = 0; ci < 4; ci++) {
      int c = wv + ci * 4;
      float kh = part[0][c][l] + part[1][c][l] + part[2][c][l] + part[3][c][l];
      float mu = wave_sum(kh) * (1.f / 64.f);
      float xc = kh - mu;
      float var = wave_sum(xc * xc) * (1.f / 64.f);
      float rstd = rsqrtf(var + EPSF);
      float xhat = xc * rstd;
      float y = xhat * w_l + b_l;
      float dy = 2.f * (y - v_s[c][l]);
      float wdy = dy * w_l;
      float c1 = wave_sum(xhat * wdy) * (1.f / 64.f);
      float c2 = wave_sum(wdy) * (1.f / 64.f);
      dkh_s[c][l] = (wdy - xhat * c1 - c2) * rstd;
    }
    __syncthreads();

    // ---- token scan: m = eta*m - theta*(k ⊗ dkh); S = (1-alpha)*S + m; o_t = q_t @ S_t ----
#pragma unroll 4
    for (int t = 0; t < CSZ; t++) {
      float th = th_s[t], al = al_s[t], et = et_s[t];
      float a = th * dkh_s[t][l];
      float one_m_al = 1.f - al;
      float kf[16], qf[16];
      *(float4*)&kf[0]  = *(const float4*)&k_s[t][wv * 16];
      *(float4*)&kf[4]  = *(const float4*)&k_s[t][wv * 16 + 4];
      *(float4*)&kf[8]  = *(const float4*)&k_s[t][wv * 16 + 8];
      *(float4*)&kf[12] = *(const float4*)&k_s[t][wv * 16 + 12];
      *(float4*)&qf[0]  = *(const float4*)&q_s[t][wv * 16];
      *(float4*)&qf[4]  = *(const float4*)&q_s[t][wv * 16 + 4];
      *(float4*)&qf[8]  = *(const float4*)&q_s[t][wv * 16 + 8];
      *(float4*)&qf[12] = *(const float4*)&q_s[t][wv * 16 + 12];
      float po = 0.f;
#pragma unroll
      for (int r = 0; r < 16; r++) {
        M[r] = et * M[r] - a * kf[r];
        S[r] = one_m_al * S[r] + M[r];
        po += qf[r] * S[r];
      }
      part[wv][t][l] = po;
    }
    __syncthreads();

    // ---- o reduce + final LN + store into v-slot ----
#pragma unroll
    for (int ci = 0; ci < 4; ci++) {
      int t = wv + ci * 4;
      float o = part[0][t][l] + part[1][t][l] + part[2][t][l] + part[3][t][l];
      float mu = wave_sum(o) * (1.f / 64.f);
      float xc = o - mu;
      float var = wave_sum(xc * xc) * (1.f / 64.f);
      float rstd = rsqrtf(var + EPSF);
      float y = xc * rstd * w_l + b_l;
      qbase[(size_t)(nt * CSZ + t) * 3072 + 2048 + l] = y;
    }
    __syncthreads();
  }
}

extern "C" void kernel_launch(void* const* d_in, const int* in_sizes, int n_in,
                              void* d_out, int out_size, void* d_ws, size_t ws_size,
                              hipStream_t stream) {
  const float* x      = (const float*)d_in[0];
  const float* W_attn = (const float*)d_in[1];
  const float* b_attn = (const float*)d_in[2];
  const float* W_parm = (const float*)d_in[3];
  const float* b_parm = (const float*)d_in[4];
  const float* W_proj = (const float*)d_in[5];
  const float* b_proj = (const float*)d_in[6];
  const float* w      = (const float*)d_in[7];
  const float* bb     = (const float*)d_in[8];
  float* out = (float*)d_out;

  const int M = BB * TT;        // 8192
  float* qkv = (float*)d_ws;                          // M x 3072
  float* pbf = qkv + (size_t)M * 3072;                // M x 48

  // qkv = x @ W_attn + b_attn
  gemm_f32<<<dim3(3072 / 128, M / 128), 256, 0, stream>>>(x, CCH, W_attn, b_attn, qkv, M, 3072, CCH);
  // p = x @ W_param + b_param (sigmoid applied at use)
  gemm_f32<<<dim3(1, M / 128), 256, 0, stream>>>(x, CCH, W_parm, b_parm, pbf, M, 48, CCH);
  // L2 normalize q, k rows
  normalize_qk<<<(M * 2 * HH) / 4, 256, 0, stream>>>(qkv);
  // recurrence; writes LN(o) into v-slot (col offset 2048)
  titans_rec<<<BB * HH, 256, 0, stream>>>(qkv, pbf, w, bb);
  // out = o @ W_proj + b_proj  (A = v-slot, lda = 3072)
  gemm_f32<<<dim3(CCH / 128, M / 128), 256, 0, stream>>>(qkv + 2048, 3072, W_proj, b_proj, out, M, CCH, CCH);
}